// Round 1
// baseline (69.779 us; speedup 1.0000x reference)
//
#include <hip/hip_runtime.h>
#include <hip/hip_bf16.h>
#include <cstdint>
#include <cmath>

// Problem constants
#define LSEQ 512
#define EDIM 64
#define NBATCH 16
#define NHEADS 8
#define NBIG 8192   // NBATCH * NHEADS * EDIM = total n dimension
#define KPAD 3

typedef __attribute__((ext_vector_type(8))) short short8;
typedef __attribute__((ext_vector_type(8))) unsigned short ushort8v;
typedef __attribute__((ext_vector_type(4))) float f32x4;

__device__ __forceinline__ unsigned short f2bf(float f) {
    union { float f; unsigned int u; } x; x.f = f;
    unsigned int r = x.u + 0x7FFFu + ((x.u >> 16) & 1u);
    return (unsigned short)(r >> 16);
}

__device__ __forceinline__ void async_copy16(void* lds, const void* g) {
    auto g1 = (const __attribute__((address_space(1))) void*)g;
    auto l3 = (__attribute__((address_space(3))) void*)lds;
    __builtin_amdgcn_global_load_lds(g1, l3, 16, 0, 0);
}

// ---------------------------------------------------------------------------
// prep_u: build Ut_bf16[m][j] = U[j][m]  and  Ub_bf16[i][m] = U[i][m]
// grid 64 (8x8 tiles of 64x64), block 256
__global__ void prep_u_kernel(const float* __restrict__ U,
                              unsigned short* __restrict__ Ut,
                              unsigned short* __restrict__ Ub) {
    __shared__ float Ls[64][65];
    int id = blockIdx.x;
    int j0 = (id >> 3) * 64, m0 = (id & 7) * 64;
    int t = threadIdx.x;
    int r = t >> 2, cq = (t & 3) * 16;

    float v[16];
    const float* src = U + (j0 + r) * LSEQ + m0 + cq;
    #pragma unroll
    for (int q = 0; q < 16; q += 4) {
        float4 vv = *(const float4*)(src + q);
        v[q] = vv.x; v[q+1] = vv.y; v[q+2] = vv.z; v[q+3] = vv.w;
    }
    // straight copy (bf16)
    {
        unsigned short ub[16];
        #pragma unroll
        for (int q = 0; q < 16; ++q) ub[q] = f2bf(v[q]);
        unsigned short* dst = Ub + (j0 + r) * LSEQ + m0 + cq;
        *(ushort8v*)dst = *(const ushort8v*)ub;
        *(ushort8v*)(dst + 8) = *(const ushort8v*)(ub + 8);
    }
    #pragma unroll
    for (int q = 0; q < 16; ++q) Ls[r][cq + q] = v[q];
    __syncthreads();
    // transposed: Ut[m0+r][j0+cq+q] = U[j0+cq+q][m0+r] = Ls[cq+q][r]
    {
        unsigned short o[16];
        #pragma unroll
        for (int q = 0; q < 16; ++q) o[q] = f2bf(Ls[cq + q][r]);
        unsigned short* dst = Ut + (m0 + r) * LSEQ + j0 + cq;
        *(ushort8v*)dst = *(const ushort8v*)o;
        *(ushort8v*)(dst + 8) = *(const ushort8v*)(o + 8);
    }
}

// ---------------------------------------------------------------------------
// prep_v: V''[n][j] = values[b][j][hd] as bf16, n = b*512 + hd
// grid 1024 (b x 8 j-tiles x 8 hd-tiles of 64x64), block 256
__global__ void prep_v_kernel(const float* __restrict__ vals,
                              unsigned short* __restrict__ Vpp) {
    __shared__ float Ls[64][65];
    int id = blockIdx.x;
    int b = id >> 6, jt = (id >> 3) & 7, ht = id & 7;
    int j0 = jt * 64, hd0 = ht * 64;
    int t = threadIdx.x;
    int r = t >> 2, cq = (t & 3) * 16;

    const float* src = vals + (size_t)b * (LSEQ * 512) + (j0 + r) * 512 + hd0 + cq;
    #pragma unroll
    for (int q = 0; q < 16; q += 4) {
        float4 vv = *(const float4*)(src + q);
        Ls[r][cq + q]     = vv.x;
        Ls[r][cq + q + 1] = vv.y;
        Ls[r][cq + q + 2] = vv.z;
        Ls[r][cq + q + 3] = vv.w;
    }
    __syncthreads();
    unsigned short o[16];
    #pragma unroll
    for (int q = 0; q < 16; ++q) o[q] = f2bf(Ls[cq + q][r]);
    unsigned short* dst = Vpp + (size_t)(b * 512 + hd0 + r) * LSEQ + j0 + cq;
    *(ushort8v*)dst = *(const ushort8v*)o;
    *(ushort8v*)(dst + 8) = *(const ushort8v*)(o + 8);
}

// ---------------------------------------------------------------------------
// conv + lambda + inv: inv[bh][l] = 1/(1 + (1+elu(conv(V)+cb)) * S[l])
// grid 128 (b*h), block 512 (thread = l)
__global__ void conv_inv_kernel(const float* __restrict__ vals,
                                const float* __restrict__ cw,
                                const float* __restrict__ cb,
                                const float* __restrict__ S,
                                float* __restrict__ inv) {
    __shared__ float wl[7][64];
    int bh = blockIdx.x;
    int b = bh >> 3, h = bh & 7;
    int t = threadIdx.x;  // l
    if (t < 448) { int e = t / 7, k = t % 7; wl[k][e] = cw[t]; }
    __syncthreads();

    float y = cb[0];
    const float* base = vals + (size_t)b * (LSEQ * 512) + h * EDIM;
    #pragma unroll
    for (int k = 0; k < 7; ++k) {
        int row = t - KPAD + k;
        row = row < 0 ? 0 : (row > LSEQ - 1 ? LSEQ - 1 : row);
        const float4* vp = (const float4*)(base + (size_t)row * 512);
        const float* wk = wl[k];
        #pragma unroll
        for (int eq = 0; eq < 16; ++eq) {
            float4 v = vp[eq];
            y += v.x * wk[eq*4] + v.y * wk[eq*4+1] + v.z * wk[eq*4+2] + v.w * wk[eq*4+3];
        }
    }
    float lam = (y > 0.f) ? (1.f + y) : expf(y);   // 1 + elu(y)
    inv[bh * LSEQ + t] = 1.f / (1.f + lam * S[t]);
}

// ---------------------------------------------------------------------------
// GEMM: C[M=512][N=8192] = A[512x512] * B (B stored n-major k-contig: Bm[n][k])
// EPI=1: write T''[n][m] = bf16(C[m][n] * inv[n>>6][m])
// EPI=2: write out[b][m][hd] = C[m][n],  n = b*512 + hd
template<int EPI>
__launch_bounds__(256, 2)
__global__ void gemm_kernel(const unsigned short* __restrict__ A,
                            const unsigned short* __restrict__ Bm,
                            const float* __restrict__ inv,
                            unsigned short* __restrict__ Tout,
                            float* __restrict__ Out) {
    __shared__ __align__(16) unsigned short As[128 * 32];
    __shared__ __align__(16) unsigned short Bs[128 * 32];

    int bid = blockIdx.x;
    int mt = bid & 3, nt = bid >> 2;
    int m0 = mt * 128, n0 = nt * 128;
    int t = threadIdx.x;
    int lane = t & 63, wave = t >> 6;
    int wm = wave >> 1, wn = wave & 1;
    int l15 = lane & 15, l4 = lane >> 4;

    f32x4 acc[4][4] = {};

    const unsigned short* Abase = A + (size_t)(m0 + (t >> 2)) * LSEQ + (t & 3) * 8;
    const unsigned short* Bbase = Bm + (size_t)(n0 + (t >> 2)) * LSEQ + (t & 3) * 8;
    unsigned short* AsP = As + t * 8;
    unsigned short* BsP = Bs + t * 8;

    for (int kk = 0; kk < 16; ++kk) {
        int ko = kk * 32;
        async_copy16(AsP,        Abase + ko);
        async_copy16(AsP + 2048, Abase + (size_t)64 * LSEQ + ko);
        async_copy16(BsP,        Bbase + ko);
        async_copy16(BsP + 2048, Bbase + (size_t)64 * LSEQ + ko);
        __syncthreads();

        short8 a[4], bfr[4];
        #pragma unroll
        for (int i = 0; i < 4; ++i) {
            int row = wm * 64 + i * 16 + l15;
            a[i] = *(const short8*)&As[row * 32 + l4 * 8];
        }
        #pragma unroll
        for (int j = 0; j < 4; ++j) {
            int row = wn * 64 + j * 16 + l15;
            bfr[j] = *(const short8*)&Bs[row * 32 + l4 * 8];
        }
        #pragma unroll
        for (int i = 0; i < 4; ++i)
            #pragma unroll
            for (int j = 0; j < 4; ++j)
                acc[i][j] = __builtin_amdgcn_mfma_f32_16x16x32_bf16(a[i], bfr[j], acc[i][j], 0, 0, 0);
        __syncthreads();
    }

    #pragma unroll
    for (int i = 0; i < 4; ++i) {
        int mb = m0 + wm * 64 + i * 16 + l4 * 4;
        #pragma unroll
        for (int j = 0; j < 4; ++j) {
            int n = n0 + wn * 64 + j * 16 + l15;
            f32x4 v = acc[i][j];
            if (EPI == 1) {
                int bh = n >> 6;
                float4 s = *(const float4*)&inv[bh * LSEQ + mb];
                ushort4 pack;
                pack.x = f2bf(v[0] * s.x);
                pack.y = f2bf(v[1] * s.y);
                pack.z = f2bf(v[2] * s.z);
                pack.w = f2bf(v[3] * s.w);
                *(ushort4*)&Tout[(size_t)n * LSEQ + mb] = pack;
            } else {
                int b = n >> 9, hd = n & 511;
                float* o = Out + (size_t)b * (LSEQ * 512) + (size_t)mb * 512 + hd;
                o[0] = v[0]; o[512] = v[1]; o[1024] = v[2]; o[1536] = v[3];
            }
        }
    }
}

// ---------------------------------------------------------------------------
extern "C" void kernel_launch(void* const* d_in, const int* in_sizes, int n_in,
                              void* d_out, int out_size, void* d_ws, size_t ws_size,
                              hipStream_t stream) {
    const float* vals = (const float*)d_in[0];
    const float* cw   = (const float*)d_in[1];
    const float* cb   = (const float*)d_in[2];
    const float* U    = (const float*)d_in[3];
    const float* S    = (const float*)d_in[4];
    float* out = (float*)d_out;

    // ws layout
    const size_t off_Ut  = 0;              // 512*512*2 = 524288
    const size_t off_Ub  = 524288;         // 524288
    const size_t off_V   = 1048576;        // 8192*512*2 = 8388608
    const size_t off_T   = 9437184;        // 8388608
    const size_t off_inv = 17825792;       // 128*512*4 = 262144
    const size_t ws_need = 18087936;
    if (ws_size < ws_need) return;  // scratch too small; fail visibly

    char* ws = (char*)d_ws;
    unsigned short* Ut  = (unsigned short*)(ws + off_Ut);
    unsigned short* Ub  = (unsigned short*)(ws + off_Ub);
    unsigned short* Vpp = (unsigned short*)(ws + off_V);
    unsigned short* Tpp = (unsigned short*)(ws + off_T);
    float*          inv = (float*)(ws + off_inv);

    prep_u_kernel<<<64, 256, 0, stream>>>(U, Ut, Ub);
    prep_v_kernel<<<1024, 256, 0, stream>>>(vals, Vpp);
    conv_inv_kernel<<<128, 512, 0, stream>>>(vals, cw, cb, S, inv);
    gemm_kernel<1><<<256, 256, 0, stream>>>(Ut, Vpp, inv, Tpp, nullptr);
    gemm_kernel<2><<<256, 256, 0, stream>>>(Ub, Tpp, nullptr, nullptr, out);
}

// Round 5
// 39.349 us; speedup vs baseline: 1.7733x; 1.7733x over previous
//
#include <hip/hip_runtime.h>
#include <hip/hip_bf16.h>
#include <cstdint>
#include <cmath>

// Problem constants
#define LSEQ 512
#define EDIM 64
#define NBIG 8192   // 16*8*64 total n dimension

typedef __attribute__((ext_vector_type(8))) short short8;
typedef __attribute__((ext_vector_type(8))) unsigned short ushort8v;
typedef __attribute__((ext_vector_type(4))) float f32x4;

__device__ __forceinline__ unsigned short f2bf(float f) {
    union { float f; unsigned int u; } x; x.f = f;
    unsigned int r = x.u + 0x7FFFu + ((x.u >> 16) & 1u);
    return (unsigned short)(r >> 16);
}

__device__ __forceinline__ void async_copy16(void* lds, const void* g) {
    auto g1 = (const __attribute__((address_space(1))) void*)g;
    auto l3 = (__attribute__((address_space(3))) void*)lds;
    __builtin_amdgcn_global_load_lds(g1, l3, 16, 0, 0);
}

// PLAIN 16-elem store: logical elems [cbase + q*16 .. +15] of a row.
__device__ __forceinline__ void store16_plain(unsigned short* rowptr, int cbase,
                                              int q, const unsigned short* o) {
    unsigned short* dst = rowptr + cbase + (q << 4);
    *(ushort8v*)dst = *(const ushort8v*)o;
    *(ushort8v*)(dst + 8) = *(const ushort8v*)(o + 8);
}

// ---------------------------------------------------------------------------
// Fused prep:
//  blocks 0..1023  : (b,h,jt) — stage values tile, emit Vpp bf16 [n][j]
//                    (n=b*512+h*64+e), plus conv->lambda->inv
//  blocks 1024..1087: U tiles — emit Ut[m][j]=U[j][m], Ub[i][m]=U[i][m]
__global__ __launch_bounds__(256) void prep_kernel(
        const float* __restrict__ vals, const float* __restrict__ U,
        const float* __restrict__ cw, const float* __restrict__ cb,
        const float* __restrict__ S,
        unsigned short* __restrict__ Vpp, unsigned short* __restrict__ Ut,
        unsigned short* __restrict__ Ub, float* __restrict__ inv) {
    __shared__ float Ls[70 * 65];        // stride 65 (odd) -> conflict-free both axes
    __shared__ float red[16][64];
    __shared__ float wcoef[448];
    int id = blockIdx.x;
    int t = threadIdx.x;

    if (id < 1024) {
        int b = id >> 6, h = (id >> 3) & 7, jt = id & 7;
        int j0 = jt * 64;
        // FIX (round 5): block has 256 threads; previous `if (t<448)` left
        // wcoef[256..447] uninitialized -> garbage conv weights for e>=37.
        for (int idx = t; idx < 448; idx += 256) wcoef[idx] = cw[idx];
        // load 70 rows (j0-3 .. j0+66, clamped) x 64 cols fp32
        const float* base = vals + (size_t)b * 262144 + h * 64;
        #pragma unroll
        for (int i = 0; i < 5; ++i) {
            int idx = i * 256 + t;
            if (idx < 1120) {
                int row = idx >> 4, c4 = (idx & 15) * 4;
                int grow = j0 + row - 3;
                grow = grow < 0 ? 0 : (grow > 511 ? 511 : grow);
                float4 v = *(const float4*)(base + (size_t)grow * 512 + c4);
                float* d = &Ls[row * 65 + c4];
                d[0] = v.x; d[1] = v.y; d[2] = v.z; d[3] = v.w;
            }
        }
        __syncthreads();

        // transpose -> Vpp (bf16). thread: e = t&63, q = t>>6
        {
            int e = t & 63, q = t >> 6;
            unsigned short o[16];
            #pragma unroll
            for (int jj = 0; jj < 16; ++jj)
                o[jj] = f2bf(Ls[(3 + q * 16 + jj) * 65 + e]);
            int n = b * 512 + h * 64 + e;
            store16_plain(Vpp + (size_t)n * 512, j0, q, o);
        }

        // conv partials: thread: lg = t&15 (4 l's), q16 = t>>4 (4 e's)
        {
            int lg = t & 15, q16 = t >> 4;
            int l0 = lg * 4, e0 = q16 * 4;
            float rv[10][4];
            #pragma unroll
            for (int r = 0; r < 10; ++r)
                #pragma unroll
                for (int je = 0; je < 4; ++je)
                    rv[r][je] = Ls[(l0 + r) * 65 + e0 + je];
            float a4[4] = {0.f, 0.f, 0.f, 0.f};
            #pragma unroll
            for (int kk = 0; kk < 7; ++kk) {
                #pragma unroll
                for (int je = 0; je < 4; ++je) {
                    float w = wcoef[(e0 + je) * 7 + kk];
                    #pragma unroll
                    for (int dl = 0; dl < 4; ++dl)
                        a4[dl] += rv[dl + kk][je] * w;
                }
            }
            #pragma unroll
            for (int dl = 0; dl < 4; ++dl) red[q16][l0 + dl] = a4[dl];
        }
        __syncthreads();
        if (t < 64) {
            float y = cb[0];
            #pragma unroll
            for (int g = 0; g < 16; ++g) y += red[g][t];
            float lam = (y > 0.f) ? (1.f + y) : expf(y);   // 1 + elu(y)
            inv[(size_t)(b * 8 + h) * 512 + j0 + t] = 1.f / (1.f + lam * S[j0 + t]);
        }
    } else {
        // U tile: 64x64 at (j0, m0)
        int id2 = id - 1024;
        int j0 = (id2 >> 3) * 64, m0 = (id2 & 7) * 64;
        int r = t >> 2, q = t & 3;
        int c16 = q * 16;
        float v[16];
        const float* src = U + (size_t)(j0 + r) * 512 + m0 + c16;
        #pragma unroll
        for (int k = 0; k < 16; k += 4) {
            float4 vv = *(const float4*)(src + k);
            v[k] = vv.x; v[k+1] = vv.y; v[k+2] = vv.z; v[k+3] = vv.w;
        }
        // straight copy -> Ub (row j0+r, chunk m0)
        {
            unsigned short o[16];
            #pragma unroll
            for (int k = 0; k < 16; ++k) o[k] = f2bf(v[k]);
            store16_plain(Ub + (size_t)(j0 + r) * 512, m0, q, o);
        }
        // row-major into LDS: Ls[j_local][m_local]
        #pragma unroll
        for (int k = 0; k < 16; ++k) Ls[r * 65 + c16 + k] = v[k];
        __syncthreads();
        // transposed read: o[k] = U[j0+c16+k][m0+r]  -> Ut[m0+r][j0+c16+k]
        {
            unsigned short o[16];
            #pragma unroll
            for (int k = 0; k < 16; ++k) o[k] = f2bf(Ls[(c16 + k) * 65 + r]);
            store16_plain(Ut + (size_t)(m0 + r) * 512, j0, q, o);
        }
    }
}

// ---------------------------------------------------------------------------
// GEMM: C[512][8192] = A[512x512] * B[n][k] (both bf16, plain row-major k-contig)
// tile 128m x 64n, BK=64, double-buffered; 512 blocks, 2/CU.
// EPI=1: Tpp[n][m] = bf16(C * inv).  EPI=2: out fp32.
template<int EPI>
__launch_bounds__(256, 2)
__global__ void gemm_kernel(const unsigned short* __restrict__ A,
                            const unsigned short* __restrict__ B,
                            const float* __restrict__ inv,
                            unsigned short* __restrict__ Tout,
                            float* __restrict__ Out) {
    __shared__ __align__(16) unsigned short As[2][128 * 64];
    __shared__ __align__(16) unsigned short Bs[2][64 * 64];

    int bid = blockIdx.x;
    bid = (bid & 7) * 64 + (bid >> 3);           // XCD chunked swizzle (512 % 8 == 0)
    int mt = bid & 3, nt = bid >> 2;
    int m0 = mt * 128, n0 = nt * 64;
    int t = threadIdx.x, lane = t & 63, wave = t >> 6;
    int wm = wave >> 1, wn = wave & 1;
    int l15 = lane & 15, l4 = lane >> 4;

    f32x4 acc[4][2] = {};

    const unsigned short* Ab = A + (size_t)(m0 + (t >> 3)) * 512 + (t & 7) * 8;
    const unsigned short* Bb = B + (size_t)(n0 + (t >> 3)) * 512 + (t & 7) * 8;

    auto STAGE = [&](int buf, int kk) {
        int ko = kk * 64;
        unsigned short* ap = &As[buf][t * 8];
        unsigned short* bp = &Bs[buf][t * 8];
        async_copy16(ap,        Ab + ko);
        async_copy16(ap + 2048, Ab + 32 * 512 + ko);
        async_copy16(ap + 4096, Ab + 64 * 512 + ko);
        async_copy16(ap + 6144, Ab + 96 * 512 + ko);
        async_copy16(bp,        Bb + ko);
        async_copy16(bp + 2048, Bb + 32 * 512 + ko);
    };
    auto COMPUTE = [&](int buf) {
        #pragma unroll
        for (int k2 = 0; k2 < 2; ++k2) {
            short8 a[4], bf[2];
            #pragma unroll
            for (int i = 0; i < 4; ++i) {
                int row = wm * 64 + i * 16 + l15;
                a[i] = *(const short8*)&As[buf][row * 64 + ((k2 * 4 + l4) << 3)];
            }
            #pragma unroll
            for (int j = 0; j < 2; ++j) {
                int row = wn * 32 + j * 16 + l15;
                bf[j] = *(const short8*)&Bs[buf][row * 64 + ((k2 * 4 + l4) << 3)];
            }
            #pragma unroll
            for (int i = 0; i < 4; ++i)
                #pragma unroll
                for (int j = 0; j < 2; ++j)
                    acc[i][j] = __builtin_amdgcn_mfma_f32_16x16x32_bf16(a[i], bf[j], acc[i][j], 0, 0, 0);
        }
    };

    STAGE(0, 0);
    __syncthreads();
    int cur = 0;
    #pragma unroll
    for (int kk = 0; kk < 7; ++kk) {
        STAGE(cur ^ 1, kk + 1);
        COMPUTE(cur);
        __syncthreads();
        cur ^= 1;
    }
    COMPUTE(cur);

    #pragma unroll
    for (int i = 0; i < 4; ++i) {
        int mb = m0 + wm * 64 + i * 16 + l4 * 4;
        if (EPI == 1) {
            float4 s = *(const float4*)&inv[(size_t)nt * 512 + mb];
            #pragma unroll
            for (int j = 0; j < 2; ++j) {
                int n = n0 + wn * 32 + j * 16 + l15;
                f32x4 v = acc[i][j];
                ushort4 pack;
                pack.x = f2bf(v[0] * s.x);
                pack.y = f2bf(v[1] * s.y);
                pack.z = f2bf(v[2] * s.z);
                pack.w = f2bf(v[3] * s.w);
                *(ushort4*)&Tout[(size_t)n * 512 + mb] = pack;
            }
        } else {
            #pragma unroll
            for (int j = 0; j < 2; ++j) {
                int n = n0 + wn * 32 + j * 16 + l15;
                int b = n >> 9, hd = n & 511;
                f32x4 v = acc[i][j];
                float* o = Out + (size_t)b * 262144 + (size_t)mb * 512 + hd;
                o[0] = v[0]; o[512] = v[1]; o[1024] = v[2]; o[1536] = v[3];
            }
        }
    }
}

// ---------------------------------------------------------------------------
extern "C" void kernel_launch(void* const* d_in, const int* in_sizes, int n_in,
                              void* d_out, int out_size, void* d_ws, size_t ws_size,
                              hipStream_t stream) {
    const float* vals = (const float*)d_in[0];
    const float* cw   = (const float*)d_in[1];
    const float* cb   = (const float*)d_in[2];
    const float* U    = (const float*)d_in[3];
    const float* S    = (const float*)d_in[4];
    float* out = (float*)d_out;

    const size_t off_Ut  = 0;              // 512KB
    const size_t off_Ub  = 524288;         // 512KB
    const size_t off_V   = 1048576;        // 8MB
    const size_t off_T   = 9437184;        // 8MB
    const size_t off_inv = 17825792;       // 256KB
    const size_t ws_need = 18087936;
    if (ws_size < ws_need) return;

    char* ws = (char*)d_ws;
    unsigned short* Ut  = (unsigned short*)(ws + off_Ut);
    unsigned short* Ub  = (unsigned short*)(ws + off_Ub);
    unsigned short* Vpp = (unsigned short*)(ws + off_V);
    unsigned short* Tpp = (unsigned short*)(ws + off_T);
    float*          inv = (float*)(ws + off_inv);

    prep_kernel<<<1088, 256, 0, stream>>>(vals, U, cw, cb, S, Vpp, Ut, Ub, inv);
    gemm_kernel<1><<<512, 256, 0, stream>>>(Ut, Vpp, inv, Tpp, nullptr);
    gemm_kernel<2><<<512, 256, 0, stream>>>(Ub, Tpp, nullptr, nullptr, out);
}

// Round 6
// 34.626 us; speedup vs baseline: 2.0152x; 1.1364x over previous
//
#include <hip/hip_runtime.h>
#include <hip/hip_bf16.h>
#include <cstdint>
#include <cmath>

// Problem constants
#define LSEQ 512
#define EDIM 64
#define NBIG 8192   // 16*8*64 total n dimension

typedef __attribute__((ext_vector_type(8))) short short8;
typedef __attribute__((ext_vector_type(8))) unsigned short ushort8v;
typedef __attribute__((ext_vector_type(4))) float f32x4;

__device__ __forceinline__ unsigned short f2bf(float f) {
    union { float f; unsigned int u; } x; x.f = f;
    unsigned int r = x.u + 0x7FFFu + ((x.u >> 16) & 1u);
    return (unsigned short)(r >> 16);
}

__device__ __forceinline__ void async_copy16(void* lds, const void* g) {
    auto g1 = (const __attribute__((address_space(1))) void*)g;
    auto l3 = (__attribute__((address_space(3))) void*)lds;
    __builtin_amdgcn_global_load_lds(g1, l3, 16, 0, 0);
}

// Swizzled 16-elem store: logical elems [cbase + q*16 .. +15] of row `row`;
// within the 64-elem chunk at cbase, 8-elem granule g lands at physical
// granule p = g ^ (row & 7).  (o holds logical granules 2q (lo), 2q+1 (hi).)
__device__ __forceinline__ void store16_swz(unsigned short* rowptr, int cbase,
                                            int q, int row,
                                            const unsigned short* o) {
    int x = row & 7, x1 = x >> 1, x0 = x & 1;
    unsigned short* dst = rowptr + cbase + ((q ^ x1) << 4);
    ushort8v lo = *(const ushort8v*)o;
    ushort8v hi = *(const ushort8v*)(o + 8);
    if (x0) { *(ushort8v*)dst = hi; *(ushort8v*)(dst + 8) = lo; }
    else    { *(ushort8v*)dst = lo; *(ushort8v*)(dst + 8) = hi; }
}

// ---------------------------------------------------------------------------
// Fused prep:
//  blocks 0..1023  : (b,h,jt) — stage values tile, emit Vpp bf16 swizzled [n][j]
//                    (n=b*512+h*64+e), plus conv->lambda->inv
//  blocks 1024..1087: U tiles — emit Ut[m][j]=U[j][m], Ub[i][m]=U[i][m], swizzled
__global__ __launch_bounds__(256) void prep_kernel(
        const float* __restrict__ vals, const float* __restrict__ U,
        const float* __restrict__ cw, const float* __restrict__ cb,
        const float* __restrict__ S,
        unsigned short* __restrict__ Vpp, unsigned short* __restrict__ Ut,
        unsigned short* __restrict__ Ub, float* __restrict__ inv) {
    __shared__ float Ls[70 * 65];        // stride 65 (odd) -> conflict-free both axes
    __shared__ float red[16][64];
    __shared__ float wcoef[448];
    int id = blockIdx.x;
    int t = threadIdx.x;

    if (id < 1024) {
        int b = id >> 6, h = (id >> 3) & 7, jt = id & 7;
        int j0 = jt * 64;
        // 256-thread block: strided fill of all 448 weights (round-5 fix).
        for (int idx = t; idx < 448; idx += 256) wcoef[idx] = cw[idx];
        // load 70 rows (j0-3 .. j0+66, clamped) x 64 cols fp32
        const float* base = vals + (size_t)b * 262144 + h * 64;
        #pragma unroll
        for (int i = 0; i < 5; ++i) {
            int idx = i * 256 + t;
            if (idx < 1120) {
                int row = idx >> 4, c4 = (idx & 15) * 4;
                int grow = j0 + row - 3;
                grow = grow < 0 ? 0 : (grow > 511 ? 511 : grow);
                float4 v = *(const float4*)(base + (size_t)grow * 512 + c4);
                float* d = &Ls[row * 65 + c4];
                d[0] = v.x; d[1] = v.y; d[2] = v.z; d[3] = v.w;
            }
        }
        __syncthreads();

        // transpose -> Vpp (bf16, swizzled). thread: e = t&63, q = t>>6
        {
            int e = t & 63, q = t >> 6;
            unsigned short o[16];
            #pragma unroll
            for (int jj = 0; jj < 16; ++jj)
                o[jj] = f2bf(Ls[(3 + q * 16 + jj) * 65 + e]);
            int n = b * 512 + h * 64 + e;
            store16_swz(Vpp + (size_t)n * 512, j0, q, n, o);
        }

        // conv partials: thread: lg = t&15 (4 l's), q16 = t>>4 (4 e's)
        {
            int lg = t & 15, q16 = t >> 4;
            int l0 = lg * 4, e0 = q16 * 4;
            float rv[10][4];
            #pragma unroll
            for (int r = 0; r < 10; ++r)
                #pragma unroll
                for (int je = 0; je < 4; ++je)
                    rv[r][je] = Ls[(l0 + r) * 65 + e0 + je];
            float a4[4] = {0.f, 0.f, 0.f, 0.f};
            #pragma unroll
            for (int kk = 0; kk < 7; ++kk) {
                #pragma unroll
                for (int je = 0; je < 4; ++je) {
                    float w = wcoef[(e0 + je) * 7 + kk];
                    #pragma unroll
                    for (int dl = 0; dl < 4; ++dl)
                        a4[dl] += rv[dl + kk][je] * w;
                }
            }
            #pragma unroll
            for (int dl = 0; dl < 4; ++dl) red[q16][l0 + dl] = a4[dl];
        }
        __syncthreads();
        if (t < 64) {
            float y = cb[0];
            #pragma unroll
            for (int g = 0; g < 16; ++g) y += red[g][t];
            float lam = (y > 0.f) ? (1.f + y) : expf(y);   // 1 + elu(y)
            inv[(size_t)(b * 8 + h) * 512 + j0 + t] = 1.f / (1.f + lam * S[j0 + t]);
        }
    } else {
        // U tile: 64x64 at (j0, m0)
        int id2 = id - 1024;
        int j0 = (id2 >> 3) * 64, m0 = (id2 & 7) * 64;
        int r = t >> 2, q = t & 3;
        int c16 = q * 16;
        float v[16];
        const float* src = U + (size_t)(j0 + r) * 512 + m0 + c16;
        #pragma unroll
        for (int k = 0; k < 16; k += 4) {
            float4 vv = *(const float4*)(src + k);
            v[k] = vv.x; v[k+1] = vv.y; v[k+2] = vv.z; v[k+3] = vv.w;
        }
        // straight copy -> Ub (row j0+r, chunk m0), swizzled
        {
            unsigned short o[16];
            #pragma unroll
            for (int k = 0; k < 16; ++k) o[k] = f2bf(v[k]);
            store16_swz(Ub + (size_t)(j0 + r) * 512, m0, q, j0 + r, o);
        }
        // row-major into LDS: Ls[j_local][m_local]
        #pragma unroll
        for (int k = 0; k < 16; ++k) Ls[r * 65 + c16 + k] = v[k];
        __syncthreads();
        // transposed read: o[k] = U[j0+c16+k][m0+r]  -> Ut[m0+r][j0+c16+k]
        {
            unsigned short o[16];
            #pragma unroll
            for (int k = 0; k < 16; ++k) o[k] = f2bf(Ls[(c16 + k) * 65 + r]);
            store16_swz(Ut + (size_t)(m0 + r) * 512, j0, q, m0 + r, o);
        }
    }
}

// ---------------------------------------------------------------------------
// GEMM: C[512][8192] = A[512x512] * B[n][k] (both bf16, granule-swizzled rows)
// tile 128m x 64n, BK=64, double-buffered; 512 blocks, 2/CU.
// EPI=1: Tpp[n][m] = bf16(C * inv), swizzled.  EPI=2: out fp32.
template<int EPI>
__launch_bounds__(256, 2)
__global__ void gemm_kernel(const unsigned short* __restrict__ A,
                            const unsigned short* __restrict__ B,
                            const float* __restrict__ inv,
                            unsigned short* __restrict__ Tout,
                            float* __restrict__ Out) {
    __shared__ __align__(16) unsigned short As[2][128 * 64];
    __shared__ __align__(16) unsigned short Bs[2][64 * 64];

    int bid = blockIdx.x;
    bid = (bid & 7) * 64 + (bid >> 3);           // XCD chunked swizzle (512 % 8 == 0)
    int mt = bid & 3, nt = bid >> 2;
    int m0 = mt * 128, n0 = nt * 64;
    int t = threadIdx.x, lane = t & 63, wave = t >> 6;
    int wm = wave >> 1, wn = wave & 1;
    int l15 = lane & 15, l4 = lane >> 4;

    f32x4 acc[4][2] = {};

    const unsigned short* Ab = A + (size_t)(m0 + (t >> 3)) * 512 + (t & 7) * 8;
    const unsigned short* Bb = B + (size_t)(n0 + (t >> 3)) * 512 + (t & 7) * 8;

    auto STAGE = [&](int buf, int kk) {
        int ko = kk * 64;
        unsigned short* ap = &As[buf][t * 8];
        unsigned short* bp = &Bs[buf][t * 8];
        async_copy16(ap,        Ab + ko);
        async_copy16(ap + 2048, Ab + 32 * 512 + ko);
        async_copy16(ap + 4096, Ab + 64 * 512 + ko);
        async_copy16(ap + 6144, Ab + 96 * 512 + ko);
        async_copy16(bp,        Bb + ko);
        async_copy16(bp + 2048, Bb + 32 * 512 + ko);
    };
    auto COMPUTE = [&](int buf) {
        #pragma unroll
        for (int k2 = 0; k2 < 2; ++k2) {
            short8 a[4], bf[2];
            #pragma unroll
            for (int i = 0; i < 4; ++i) {
                int row = wm * 64 + i * 16 + l15;
                a[i] = *(const short8*)&As[buf][row * 64 + (((k2 * 4 + l4) ^ (row & 7)) << 3)];
            }
            #pragma unroll
            for (int j = 0; j < 2; ++j) {
                int row = wn * 32 + j * 16 + l15;
                bf[j] = *(const short8*)&Bs[buf][row * 64 + (((k2 * 4 + l4) ^ (row & 7)) << 3)];
            }
            #pragma unroll
            for (int i = 0; i < 4; ++i)
                #pragma unroll
                for (int j = 0; j < 2; ++j)
                    acc[i][j] = __builtin_amdgcn_mfma_f32_16x16x32_bf16(a[i], bf[j], acc[i][j], 0, 0, 0);
        }
    };

    STAGE(0, 0);
    __syncthreads();
    int cur = 0;
    #pragma unroll
    for (int kk = 0; kk < 7; ++kk) {
        STAGE(cur ^ 1, kk + 1);
        COMPUTE(cur);
        __syncthreads();
        cur ^= 1;
    }
    COMPUTE(cur);

    #pragma unroll
    for (int i = 0; i < 4; ++i) {
        int mb = m0 + wm * 64 + i * 16 + l4 * 4;
        if (EPI == 1) {
            float4 s = *(const float4*)&inv[(size_t)nt * 512 + mb];
            #pragma unroll
            for (int j = 0; j < 2; ++j) {
                int n = n0 + wn * 32 + j * 16 + l15;
                f32x4 v = acc[i][j];
                ushort4 pack;
                pack.x = f2bf(v[0] * s.x);
                pack.y = f2bf(v[1] * s.y);
                pack.z = f2bf(v[2] * s.z);
                pack.w = f2bf(v[3] * s.w);
                int e = mb & 63;
                int pos = (mb & ~63) + ((((e >> 3) ^ (n & 7)) << 3) | (e & 7));
                *(ushort4*)&Tout[(size_t)n * 512 + pos] = pack;
            }
        } else {
            #pragma unroll
            for (int j = 0; j < 2; ++j) {
                int n = n0 + wn * 32 + j * 16 + l15;
                int b = n >> 9, hd = n & 511;
                f32x4 v = acc[i][j];
                float* o = Out + (size_t)b * 262144 + (size_t)mb * 512 + hd;
                o[0] = v[0]; o[512] = v[1]; o[1024] = v[2]; o[1536] = v[3];
            }
        }
    }
}

// ---------------------------------------------------------------------------
extern "C" void kernel_launch(void* const* d_in, const int* in_sizes, int n_in,
                              void* d_out, int out_size, void* d_ws, size_t ws_size,
                              hipStream_t stream) {
    const float* vals = (const float*)d_in[0];
    const float* cw   = (const float*)d_in[1];
    const float* cb   = (const float*)d_in[2];
    const float* U    = (const float*)d_in[3];
    const float* S    = (const float*)d_in[4];
    float* out = (float*)d_out;

    const size_t off_Ut  = 0;              // 512KB
    const size_t off_Ub  = 524288;         // 512KB
    const size_t off_V   = 1048576;        // 8MB
    const size_t off_T   = 9437184;        // 8MB
    const size_t off_inv = 17825792;       // 256KB
    const size_t ws_need = 18087936;
    if (ws_size < ws_need) return;

    char* ws = (char*)d_ws;
    unsigned short* Ut  = (unsigned short*)(ws + off_Ut);
    unsigned short* Ub  = (unsigned short*)(ws + off_Ub);
    unsigned short* Vpp = (unsigned short*)(ws + off_V);
    unsigned short* Tpp = (unsigned short*)(ws + off_T);
    float*          inv = (float*)(ws + off_inv);

    prep_kernel<<<1088, 256, 0, stream>>>(vals, U, cw, cb, S, Vpp, Ut, Ub, inv);
    gemm_kernel<1><<<512, 256, 0, stream>>>(Ut, Vpp, inv, Tpp, nullptr);
    gemm_kernel<2><<<512, 256, 0, stream>>>(Ub, Tpp, nullptr, nullptr, out);
}